// Round 6
// baseline (25.978 us; speedup 1.0000x reference)
//
#include <hip/hip_runtime.h>

// out[i] = Re(state[i] * factor)   (harness: out_size == N, real part)
// factor = prod over 30 gates of (2 cos(a) cos(b) + 2j sin(a) sin(g)).
// Every wave computes the factor redundantly in-register (fast-trig +
// 6-step shuffle butterfly). Grid 2048 = exactly one resident cohort
// (8 blocks/CU) so the preamble is paid once per SIMD. First state load
// issues BEFORE the trig so the ~900cy HBM latency hides the preamble.
// Plain (caching) loads/stores: 64MiB in + 64MiB out fits the 256MiB L3,
// so steady-state graph replays can run at L3 speed. (NT stores measured
// ~neutral and force HBM traffic -- removed.)

typedef float fvec4 __attribute__((ext_vector_type(4)));

__device__ __forceinline__ float2 wave_factor(const float* __restrict__ gp) {
    const int lane = threadIdx.x & 63;
    float re = 1.0f, im = 0.0f;
    if (lane < 30) {
        const float a = gp[lane * 4 + 0];
        const float b = gp[lane * 4 + 1];
        const float g = gp[lane * 4 + 2];
        re = 2.0f * __cosf(a) * __cosf(b);
        im = 2.0f * __sinf(a) * __sinf(g);
    }
    #pragma unroll
    for (int m = 1; m < 64; m <<= 1) {
        const float ore = __shfl_xor(re, m, 64);
        const float oim = __shfl_xor(im, m, 64);
        const float nre = re * ore - im * oim;
        const float nim = re * oim + im * ore;
        re = nre;
        im = nim;
    }
    return make_float2(re, im);
}

// Real-only output path (out_size == N): out = state * fr.
// Software-pipelined grid-stride: load(i+stride) in flight while storing i.
__global__ void __launch_bounds__(256) qp_real_kernel(const float* __restrict__ state,
                                                      const float* __restrict__ gp,
                                                      float* __restrict__ out,
                                                      long long n4 /* N/4 */) {
    const fvec4* __restrict__ in4 = reinterpret_cast<const fvec4*>(state);
    fvec4* __restrict__ out4 = reinterpret_cast<fvec4*>(out);
    const long long stride = (long long)gridDim.x * blockDim.x;
    long long i = (long long)blockIdx.x * blockDim.x + threadIdx.x;
    if (i >= n4) return;

    fvec4 s = in4[i];                      // issue first load before trig
    const float fr = wave_factor(gp).x;    // overlaps load latency

    while (i + stride < n4) {
        fvec4 nxt = in4[i + stride];       // prefetch next iter
        out4[i] = s * fr;
        s = nxt;
        i += stride;
    }
    out4[i] = s * fr;
}

// Defensive: complex64 interleaved output path (out_size == 2N).
__global__ void __launch_bounds__(256) qp_complex_kernel(const float* __restrict__ state,
                                                         const float* __restrict__ gp,
                                                         float* __restrict__ out,
                                                         long long n2 /* N/2 */) {
    const float2* __restrict__ in2 = reinterpret_cast<const float2*>(state);
    fvec4* __restrict__ out4 = reinterpret_cast<fvec4*>(out);
    const long long stride = (long long)gridDim.x * blockDim.x;
    long long i = (long long)blockIdx.x * blockDim.x + threadIdx.x;
    if (i >= n2) return;

    float2 s = in2[i];
    const float2 f = wave_factor(gp);
    const float fr = f.x, fi = f.y;

    while (i + stride < n2) {
        float2 nxt = in2[i + stride];
        fvec4 o;
        o.x = s.x * fr;
        o.y = s.x * fi;
        o.z = s.y * fr;
        o.w = s.y * fi;
        out4[i] = o;
        s = nxt;
        i += stride;
    }
    fvec4 o;
    o.x = s.x * fr;
    o.y = s.x * fi;
    o.z = s.y * fr;
    o.w = s.y * fi;
    out4[i] = o;
}

extern "C" void kernel_launch(void* const* d_in, const int* in_sizes, int n_in,
                              void* d_out, int out_size, void* d_ws, size_t ws_size,
                              hipStream_t stream) {
    const float* state = (const float*)d_in[0];
    const float* gp = (const float*)d_in[1];
    float* out = (float*)d_out;

    const long long N = (long long)in_sizes[0];  // 16,777,216

    const int block = 256;
    const int grid = 2048;  // 8 blocks/CU: exactly one resident cohort

    if ((long long)out_size == 2 * N) {
        qp_complex_kernel<<<grid, block, 0, stream>>>(state, gp, out, N / 2);
    } else {
        qp_real_kernel<<<grid, block, 0, stream>>>(state, gp, out, N / 4);
    }
}

// Round 7
// 25.295 us; speedup vs baseline: 1.0270x; 1.0270x over previous
//
#include <hip/hip_runtime.h>

// out[i] = Re(state[i] * factor)   (harness: out_size == N, real part)
// factor = prod over 30 gates of (2 cos(a) cos(b) + 2j sin(a) sin(g)).
// One-shot layout: exactly one float4 load + one float4 store per thread
// (16384x256 for N=16M), no grid-stride loop -- maximizes loads in flight
// as blocks stream through CUs (matches the ~6.8TB/s fill kernel's shape).
// Per-wave factor (fast trig + 6-step shuffle butterfly) is computed AFTER
// the state load is issued, hiding under the ~900cy HBM latency.

typedef float fvec4 __attribute__((ext_vector_type(4)));

__device__ __forceinline__ float2 wave_factor(const float* __restrict__ gp) {
    const int lane = threadIdx.x & 63;
    float re = 1.0f, im = 0.0f;
    if (lane < 30) {
        const float a = gp[lane * 4 + 0];
        const float b = gp[lane * 4 + 1];
        const float g = gp[lane * 4 + 2];
        re = 2.0f * __cosf(a) * __cosf(b);
        im = 2.0f * __sinf(a) * __sinf(g);
    }
    #pragma unroll
    for (int m = 1; m < 64; m <<= 1) {
        const float ore = __shfl_xor(re, m, 64);
        const float oim = __shfl_xor(im, m, 64);
        const float nre = re * ore - im * oim;
        const float nim = re * oim + im * ore;
        re = nre;
        im = nim;
    }
    return make_float2(re, im);
}

// Real-only path (out_size == N): one float4 per thread.
__global__ void __launch_bounds__(256) qp_real_kernel(const float* __restrict__ state,
                                                      const float* __restrict__ gp,
                                                      float* __restrict__ out,
                                                      long long n4 /* N/4 */) {
    const long long i = (long long)blockIdx.x * blockDim.x + threadIdx.x;
    if (i >= n4) return;
    const fvec4* __restrict__ in4 = reinterpret_cast<const fvec4*>(state);
    fvec4* __restrict__ out4 = reinterpret_cast<fvec4*>(out);

    fvec4 s = in4[i];                    // load issued first
    const float fr = wave_factor(gp).x;  // hides under load latency
    out4[i] = s * fr;
}

// Defensive: complex64 interleaved path (out_size == 2N): one float2-in /
// float4-out per thread.
__global__ void __launch_bounds__(256) qp_complex_kernel(const float* __restrict__ state,
                                                         const float* __restrict__ gp,
                                                         float* __restrict__ out,
                                                         long long n2 /* N/2 */) {
    const long long i = (long long)blockIdx.x * blockDim.x + threadIdx.x;
    if (i >= n2) return;
    const float2* __restrict__ in2 = reinterpret_cast<const float2*>(state);
    fvec4* __restrict__ out4 = reinterpret_cast<fvec4*>(out);

    float2 s = in2[i];
    const float2 f = wave_factor(gp);
    fvec4 o;
    o.x = s.x * f.x;
    o.y = s.x * f.y;
    o.z = s.y * f.x;
    o.w = s.y * f.y;
    out4[i] = o;
}

extern "C" void kernel_launch(void* const* d_in, const int* in_sizes, int n_in,
                              void* d_out, int out_size, void* d_ws, size_t ws_size,
                              hipStream_t stream) {
    const float* state = (const float*)d_in[0];
    const float* gp = (const float*)d_in[1];
    float* out = (float*)d_out;

    const long long N = (long long)in_sizes[0];  // 16,777,216
    const int block = 256;

    if ((long long)out_size == 2 * N) {
        const long long n2 = N / 2;
        const int grid = (int)((n2 + block - 1) / block);
        qp_complex_kernel<<<grid, block, 0, stream>>>(state, gp, out, n2);
    } else {
        const long long n4 = N / 4;
        const int grid = (int)((n4 + block - 1) / block);  // 16384
        qp_real_kernel<<<grid, block, 0, stream>>>(state, gp, out, n4);
    }
}